// Round 4
// baseline (435.716 us; speedup 1.0000x reference)
//
#include <hip/hip_runtime.h>

#define DIMN 1024
#define TN 4096
#define BN 8
#define CBN 4096
#define CDN 8
#define BTN (BN*TN)
#define OUT_ELEMS (BN*DIMN*TN)

// ws layout (float offsets)
#define WS_WINT 0          // W_in^T scaled: [d][8], 8192 floats
#define WS_WOUT 8192       // W_out scaled: [o][8], 8192 floats
#define WS_CN   16384      // normalized codebook [j][8], 32768 floats
#define WS_C2   49152      // sum(c_n^2) per code, 4096 floats
#define WS_ZE   53248      // z_e [b*T + t][8], 262144 floats
#define WS_IDX  315392     // indices (int), 32768
#define WS_LOSS 348160     // 8 floats

__device__ __forceinline__ float dot4(float4 a, float4 b) {
    float d = a.x * b.x;
    d = fmaf(a.y, b.y, d);
    d = fmaf(a.z, b.z, d);
    d = fmaf(a.w, b.w, d);
    return d;
}

// ---------------- K0: prep weights / codebook / zero loss ----------------
__global__ __launch_bounds__(256) void k0_prep(
    const float* __restrict__ v_in, const float* __restrict__ g_in,
    const float* __restrict__ codebook, const float* __restrict__ v_out,
    const float* __restrict__ g_out, float* __restrict__ ws) {
    __shared__ float sred[5];
    int blk = blockIdx.x, tid = threadIdx.x;
    if (blk < 8) {
        // weight_norm row o of v_in -> W_in^T[d][o]
        int o = blk;
        const float* v = v_in + o * DIMN;
        float4 x = *(const float4*)(v + tid * 4);
        float p = x.x * x.x + x.y * x.y + x.z * x.z + x.w * x.w;
        for (int off = 32; off >= 1; off >>= 1) p += __shfl_down(p, off, 64);
        if ((tid & 63) == 0) sred[tid >> 6] = p;
        __syncthreads();
        if (tid == 0) {
            float tot = sred[0] + sred[1] + sred[2] + sred[3];
            sred[4] = g_in[o] / sqrtf(tot);
        }
        __syncthreads();
        float s = sred[4];
        ws[WS_WINT + (tid * 4 + 0) * 8 + o] = x.x * s;
        ws[WS_WINT + (tid * 4 + 1) * 8 + o] = x.y * s;
        ws[WS_WINT + (tid * 4 + 2) * 8 + o] = x.z * s;
        ws[WS_WINT + (tid * 4 + 3) * 8 + o] = x.w * s;
    } else if (blk < 12) {
        // weight_norm rows of v_out -> W_out scaled [o][8]
        int r = (blk - 8) * 256 + tid;
        const float* v = v_out + r * 8;
        float4 a = *(const float4*)v;
        float4 b = *(const float4*)(v + 4);
        float n2 = dot4(a, a) + dot4(b, b);
        float s = g_out[r] / sqrtf(n2);
        *(float4*)(ws + WS_WOUT + r * 8)     = make_float4(a.x*s, a.y*s, a.z*s, a.w*s);
        *(float4*)(ws + WS_WOUT + r * 8 + 4) = make_float4(b.x*s, b.y*s, b.z*s, b.w*s);
    } else if (blk < 28) {
        // l2-normalize codebook rows, store c_n and sum(c_n^2)
        int j = (blk - 12) * 256 + tid;
        const float* c = codebook + j * 8;
        float4 a = *(const float4*)c;
        float4 b = *(const float4*)(c + 4);
        float n2 = dot4(a, a) + dot4(b, b);
        float inv = 1.0f / fmaxf(sqrtf(n2), 1e-12f);
        float4 na = make_float4(a.x*inv, a.y*inv, a.z*inv, a.w*inv);
        float4 nb = make_float4(b.x*inv, b.y*inv, b.z*inv, b.w*inv);
        *(float4*)(ws + WS_CN + j * 8)     = na;
        *(float4*)(ws + WS_CN + j * 8 + 4) = nb;
        ws[WS_C2 + j] = dot4(na, na) + dot4(nb, nb);
    } else {
        if (tid < 8) ws[WS_LOSS + tid] = 0.0f;
    }
}

// ---------------- K1a: z_e = W_in @ z + b_in  -> ws[WS_ZE] ----------------
// grid 256: b = blk/32, t-tile of 128. 4 waves split d into 256-chunks.
__global__ __launch_bounds__(256) void k1a_ze(
    const float* __restrict__ z, const float* __restrict__ b_in,
    float* __restrict__ ws) {
    __shared__ float wlds[8192];        // W_in^T [d][8]
    __shared__ float plds[4 * 128 * 8]; // partials [wave][t_local][c]
    int tid = threadIdx.x, blk = blockIdx.x;
    int b = blk >> 5;
    int tt0 = (blk & 31) * 128;
    #pragma unroll
    for (int i = 0; i < 8; i++) {
        int f4 = tid + i * 256;
        *(float4*)(wlds + f4 * 4) = *(const float4*)(ws + WS_WINT + f4 * 4);
    }
    __syncthreads();
    int wave = tid >> 6, lane = tid & 63;
    int d0 = wave * 256;
    const float* zp = z + ((size_t)(b * DIMN + d0)) * TN + tt0 + lane * 2;
    float acc[16];
    #pragma unroll
    for (int i = 0; i < 16; i++) acc[i] = 0.0f;
    #pragma unroll 8
    for (int d = 0; d < 256; ++d) {
        float2 zv = *(const float2*)(zp + (size_t)d * TN);
        const float* wv = wlds + (d0 + d) * 8;   // wave-uniform -> broadcast
        #pragma unroll
        for (int c = 0; c < 8; c++) {
            float w = wv[c];
            acc[c * 2]     = fmaf(w, zv.x, acc[c * 2]);
            acc[c * 2 + 1] = fmaf(w, zv.y, acc[c * 2 + 1]);
        }
    }
    float* pl = plds + (wave * 128 + lane * 2) * 8;
    #pragma unroll
    for (int c = 0; c < 8; c++) { pl[c] = acc[c * 2]; pl[8 + c] = acc[c * 2 + 1]; }
    __syncthreads();
    // reduce 4 partials, add b_in, store float4
    int f0 = tid * 4;
    int t = f0 >> 3, c0 = f0 & 7;
    float4 s = make_float4(0.f, 0.f, 0.f, 0.f);
    #pragma unroll
    for (int w = 0; w < 4; w++) {
        float4 p = *(float4*)(plds + ((w * 128 + t) * 8 + c0));
        s.x += p.x; s.y += p.y; s.z += p.z; s.w += p.w;
    }
    float4 bi = *(const float4*)(b_in + c0);
    s.x += bi.x; s.y += bi.y; s.z += bi.z; s.w += bi.w;
    *(float4*)(ws + WS_ZE + (size_t)(b * TN + tt0 + t) * 8 + c0) = s;
}

// ---------------- K1b: argmin search -> WS_IDX (int) + loss partials (ws ONLY) ----------------
// grid 512 x 512 threads: 64 t-columns/block, 8 waves = 8 code-chunks of 512.
__global__ __launch_bounds__(512) void k1b_search(
    const float* __restrict__ codebook, float* __restrict__ ws) {
    __shared__ float cd_s[8 * 64];
    __shared__ int   ci_s[8 * 64];
    int tid = threadIdx.x, blk = blockIdx.x;
    int chunk = tid >> 6;
    int lane = tid & 63;
    int tg = blk * 64 + lane;
    const float* zep = ws + WS_ZE + (size_t)tg * 8;
    float4 za = *(const float4*)zep;
    float4 zb = *(const float4*)(zep + 4);
    float e2 = dot4(za, za) + dot4(zb, zb);
    float inv = 1.0f / fmaxf(sqrtf(e2), 1e-12f);
    float4 ea = make_float4(za.x*inv, za.y*inv, za.z*inv, za.w*inv);
    float4 eb = make_float4(zb.x*inv, zb.y*inv, zb.z*inv, zb.w*inv);
    float en2 = dot4(ea, ea) + dot4(eb, eb);
    const float* cnp = ws + WS_CN + (size_t)chunk * 512 * 8;  // wave-uniform
    const float* c2p = ws + WS_C2 + chunk * 512;
    float best = 3.4e38f;
    int bi = 0;
    #pragma unroll 4
    for (int j = 0; j < 512; ++j) {
        float4 ca = *(const float4*)(cnp + j * 8);
        float4 cb = *(const float4*)(cnp + j * 8 + 4);
        float dt = dot4(ea, ca) + dot4(eb, cb);
        float dsc = fmaf(-2.0f, dt, en2 + c2p[j]);
        if (dsc < best) { best = dsc; bi = j; }   // strict <: first-min, matches np.argmin
    }
    cd_s[chunk * 64 + lane] = best;
    ci_s[chunk * 64 + lane] = chunk * 512 + bi;
    __syncthreads();
    if (chunk == 0) {
        float bd = cd_s[lane];
        int bix = ci_s[lane];
        #pragma unroll
        for (int w = 1; w < 8; ++w) {
            float d2 = cd_s[w * 64 + lane];
            int i2 = ci_s[w * 64 + lane];
            if (d2 < bd) { bd = d2; bix = i2; }   // ascending chunks: ties keep lowest j
        }
        // loss vs raw (un-normalized) codebook row
        const float* cq = codebook + (size_t)bix * 8;
        float4 qa = *(const float4*)cq;
        float4 qb = *(const float4*)(cq + 4);
        float4 da = make_float4(za.x-qa.x, za.y-qa.y, za.z-qa.z, za.w-qa.w);
        float4 db = make_float4(zb.x-qb.x, zb.y-qb.y, zb.z-qb.z, zb.w-qb.w);
        float l = dot4(da, da) + dot4(db, db);
        ((int*)ws)[WS_IDX + tg] = bix;
        for (int off = 32; off >= 1; off >>= 1) l += __shfl_down(l, off, 64);
        if (lane == 0) atomicAdd(ws + WS_LOSS + (tg >> 12), l);
    }
}

// ---------------- K2: out = W_out @ z_q + b_out (fp32 store) — out region ONLY ----------------
// grid 1024: b = blk>>7, t-tile 128, o-tile 256
__global__ __launch_bounds__(256) void k2_out(
    const float* __restrict__ codebook, const float* __restrict__ b_out,
    float* __restrict__ dout, const float* __restrict__ ws) {
    __shared__ float zq[8 * 128];   // [c][t]
    __shared__ float wl[256 * 8];   // W_out tile [o_local][8]
    int tid = threadIdx.x, blk = blockIdx.x;
    int b = blk >> 7;
    int rem = blk & 127;
    int t0 = (rem >> 2) * 128;
    int o0 = (rem & 3) * 256;
    const int* wsi = (const int*)ws;
    if (tid < 128) {
        int idx = wsi[WS_IDX + b * TN + t0 + tid] & (CBN - 1);  // clamp: insurance
        const float* cp = codebook + (size_t)idx * 8;
        float4 qa = *(const float4*)cp;
        float4 qb = *(const float4*)(cp + 4);
        zq[0 * 128 + tid] = qa.x; zq[1 * 128 + tid] = qa.y;
        zq[2 * 128 + tid] = qa.z; zq[3 * 128 + tid] = qa.w;
        zq[4 * 128 + tid] = qb.x; zq[5 * 128 + tid] = qb.y;
        zq[6 * 128 + tid] = qb.z; zq[7 * 128 + tid] = qb.w;
    }
    #pragma unroll
    for (int i = 0; i < 2; i++) {
        int f4 = tid + i * 256;
        *(float4*)(wl + f4 * 4) = *(const float4*)(ws + WS_WOUT + o0 * 8 + f4 * 4);
    }
    __syncthreads();
    int t4 = tid & 31, osub = tid >> 5;
    int tq = t4 * 4;
    float4 zr[8];
    #pragma unroll
    for (int c = 0; c < 8; c++) zr[c] = *(float4*)(zq + c * 128 + tq);
    for (int k = 0; k < 32; k++) {
        int ol = osub * 32 + k;
        int o = o0 + ol;
        float4 wa = *(float4*)(wl + ol * 8);
        float4 wb = *(float4*)(wl + ol * 8 + 4);
        float bo = b_out[o];
        float4 acc = make_float4(bo, bo, bo, bo);
        float wc[8] = {wa.x, wa.y, wa.z, wa.w, wb.x, wb.y, wb.z, wb.w};
        #pragma unroll
        for (int c = 0; c < 8; c++) {
            acc.x = fmaf(wc[c], zr[c].x, acc.x);
            acc.y = fmaf(wc[c], zr[c].y, acc.y);
            acc.z = fmaf(wc[c], zr[c].z, acc.z);
            acc.w = fmaf(wc[c], zr[c].w, acc.w);
        }
        // insurance clamp: legit |out| < ~0.5
        acc.x = fminf(fmaxf(acc.x, -8.f), 8.f);
        acc.y = fminf(fmaxf(acc.y, -8.f), 8.f);
        acc.z = fminf(fmaxf(acc.z, -8.f), 8.f);
        acc.w = fminf(fmaxf(acc.w, -8.f), 8.f);
        size_t off = ((size_t)(b * DIMN + o)) * TN + (size_t)(t0 + tq);
        *(float4*)(dout + off) = acc;   // fp32 store, 16B aligned
    }
}

// ---------------- K3: epilogue — fp32 indices + loss (sole writer of tail region) ----------------
__global__ __launch_bounds__(256) void k3_epi(
    float* __restrict__ dout, const float* __restrict__ ws) {
    int tid = threadIdx.x, blk = blockIdx.x;
    const int* wsi = (const int*)ws;
    size_t base = (size_t)OUT_ELEMS;
    int i0 = blk * 512 + tid;
    dout[base + (size_t)i0]       = (float)(wsi[WS_IDX + i0] & (CBN - 1));
    dout[base + (size_t)i0 + 256] = (float)(wsi[WS_IDX + i0 + 256] & (CBN - 1));
    if (blk == 0 && tid < 8) {
        float lv = ws[WS_LOSS + tid] * (1.25f / 32768.0f);
        dout[base + (size_t)BTN + (size_t)tid] = lv;
    }
}

extern "C" void kernel_launch(void* const* d_in, const int* in_sizes, int n_in,
                              void* d_out, int out_size, void* d_ws, size_t ws_size,
                              hipStream_t stream) {
    (void)in_sizes; (void)n_in; (void)out_size; (void)ws_size;
    const float* z        = (const float*)d_in[0];
    const float* v_in     = (const float*)d_in[1];
    const float* g_in     = (const float*)d_in[2];
    const float* b_in     = (const float*)d_in[3];
    const float* codebook = (const float*)d_in[4];
    const float* v_out    = (const float*)d_in[5];
    const float* g_out    = (const float*)d_in[6];
    const float* b_out    = (const float*)d_in[7];
    float* out            = (float*)d_out;
    float* ws             = (float*)d_ws;

    hipLaunchKernelGGL(k0_prep, dim3(29), dim3(256), 0, stream,
                       v_in, g_in, codebook, v_out, g_out, ws);
    hipLaunchKernelGGL(k1a_ze, dim3(256), dim3(256), 0, stream, z, b_in, ws);
    hipLaunchKernelGGL(k1b_search, dim3(512), dim3(512), 0, stream, codebook, ws);
    hipLaunchKernelGGL(k2_out, dim3(1024), dim3(256), 0, stream,
                       codebook, b_out, out, ws);
    hipLaunchKernelGGL(k3_epi, dim3(64), dim3(256), 0, stream, out, ws);
}

// Round 5
// 323.050 us; speedup vs baseline: 1.3488x; 1.3488x over previous
//
#include <hip/hip_runtime.h>

#define DIMN 1024
#define TN 4096
#define BN 8
#define CBN 4096
#define CDN 8
#define BTN (BN*TN)
#define OUT_ELEMS (BN*DIMN*TN)

// ws layout (float offsets)
#define WS_WINT 0          // W_in^T scaled: [d][8], 8192 floats
#define WS_WOUT 8192       // W_out scaled: [o][8], 8192 floats
#define WS_CN   16384      // normalized codebook [j][8], 32768 floats
#define WS_C2   49152      // h = -0.5*sum(c_n^2) per code, 4096 floats
#define WS_ZE   53248      // z_e [b*T + t][8], 262144 floats
#define WS_IDX  315392     // indices (int), 32768
#define WS_LOSS 348160     // 8 floats
#define WS_PART 348168     // partial (score,idxbits) float2 [4][32768], 262144 floats

__device__ __forceinline__ float dot4(float4 a, float4 b) {
    float d = a.x * b.x;
    d = fmaf(a.y, b.y, d);
    d = fmaf(a.z, b.z, d);
    d = fmaf(a.w, b.w, d);
    return d;
}

// ---------------- K0: prep weights / codebook / zero loss ----------------
__global__ __launch_bounds__(256) void k0_prep(
    const float* __restrict__ v_in, const float* __restrict__ g_in,
    const float* __restrict__ codebook, const float* __restrict__ v_out,
    const float* __restrict__ g_out, float* __restrict__ ws) {
    __shared__ float sred[5];
    int blk = blockIdx.x, tid = threadIdx.x;
    if (blk < 8) {
        int o = blk;
        const float* v = v_in + o * DIMN;
        float4 x = *(const float4*)(v + tid * 4);
        float p = x.x * x.x + x.y * x.y + x.z * x.z + x.w * x.w;
        for (int off = 32; off >= 1; off >>= 1) p += __shfl_down(p, off, 64);
        if ((tid & 63) == 0) sred[tid >> 6] = p;
        __syncthreads();
        if (tid == 0) {
            float tot = sred[0] + sred[1] + sred[2] + sred[3];
            sred[4] = g_in[o] / sqrtf(tot);
        }
        __syncthreads();
        float s = sred[4];
        ws[WS_WINT + (tid * 4 + 0) * 8 + o] = x.x * s;
        ws[WS_WINT + (tid * 4 + 1) * 8 + o] = x.y * s;
        ws[WS_WINT + (tid * 4 + 2) * 8 + o] = x.z * s;
        ws[WS_WINT + (tid * 4 + 3) * 8 + o] = x.w * s;
    } else if (blk < 12) {
        int r = (blk - 8) * 256 + tid;
        const float* v = v_out + r * 8;
        float4 a = *(const float4*)v;
        float4 b = *(const float4*)(v + 4);
        float n2 = dot4(a, a) + dot4(b, b);
        float s = g_out[r] / sqrtf(n2);
        *(float4*)(ws + WS_WOUT + r * 8)     = make_float4(a.x*s, a.y*s, a.z*s, a.w*s);
        *(float4*)(ws + WS_WOUT + r * 8 + 4) = make_float4(b.x*s, b.y*s, b.z*s, b.w*s);
    } else if (blk < 28) {
        int j = (blk - 12) * 256 + tid;
        const float* c = codebook + j * 8;
        float4 a = *(const float4*)c;
        float4 b = *(const float4*)(c + 4);
        float n2 = dot4(a, a) + dot4(b, b);
        float inv = 1.0f / fmaxf(sqrtf(n2), 1e-12f);
        float4 na = make_float4(a.x*inv, a.y*inv, a.z*inv, a.w*inv);
        float4 nb = make_float4(b.x*inv, b.y*inv, b.z*inv, b.w*inv);
        *(float4*)(ws + WS_CN + j * 8)     = na;
        *(float4*)(ws + WS_CN + j * 8 + 4) = nb;
        // h = -c2/2: argmin(en2 - 2 dot + c2) == argmax(dot + h)
        ws[WS_C2 + j] = -0.5f * (dot4(na, na) + dot4(nb, nb));
    } else {
        if (tid < 8) ws[WS_LOSS + tid] = 0.0f;
    }
}

// ---------------- K1a: z_e = W_in @ z + b_in  -> ws[WS_ZE] ----------------
// grid 256: b = blk>>5, t-tile 128. Block 512 = 8 waves; wave w: d-chunk [w*128,(w+1)*128)
__global__ __launch_bounds__(512) void k1a_ze(
    const float* __restrict__ z, const float* __restrict__ b_in,
    float* __restrict__ ws) {
    __shared__ float wlds[8192];        // W_in^T [d][8], 32 KB
    __shared__ float plds[8 * 128 * 8]; // partials [w][t][c], 32 KB
    int tid = threadIdx.x, blk = blockIdx.x;
    int b = blk >> 5;
    int tt0 = (blk & 31) * 128;
    #pragma unroll
    for (int i = 0; i < 4; i++) {
        int f4 = tid + i * 512;
        *(float4*)(wlds + f4 * 4) = *(const float4*)(ws + WS_WINT + f4 * 4);
    }
    __syncthreads();
    int w = tid >> 6, lane = tid & 63;
    int d0 = w * 128;
    const float* zp = z + ((size_t)(b * DIMN + d0)) * TN + tt0 + lane * 2;
    float acc[16];
    #pragma unroll
    for (int i = 0; i < 16; i++) acc[i] = 0.0f;
    #pragma unroll 8
    for (int d = 0; d < 128; ++d) {
        float2 zv = *(const float2*)(zp + (size_t)d * TN);
        const float* wv = wlds + (d0 + d) * 8;   // wave-uniform -> broadcast
        #pragma unroll
        for (int c = 0; c < 8; c++) {
            float wc = wv[c];
            acc[c * 2]     = fmaf(wc, zv.x, acc[c * 2]);
            acc[c * 2 + 1] = fmaf(wc, zv.y, acc[c * 2 + 1]);
        }
    }
    float* pl = plds + (w * 128 + lane * 2) * 8;
    *(float4*)(pl)      = make_float4(acc[0], acc[2], acc[4], acc[6]);
    *(float4*)(pl + 4)  = make_float4(acc[8], acc[10], acc[12], acc[14]);
    *(float4*)(pl + 8)  = make_float4(acc[1], acc[3], acc[5], acc[7]);
    *(float4*)(pl + 12) = make_float4(acc[9], acc[11], acc[13], acc[15]);
    __syncthreads();
    // reduce 8 partials: 1024 outputs, 2 per thread
    int f0 = tid * 2;
    int t = f0 >> 3, c0 = f0 & 7;
    float2 s = make_float2(0.f, 0.f);
    #pragma unroll
    for (int w2 = 0; w2 < 8; w2++) {
        float2 p = *(float2*)(plds + (w2 * 128 + t) * 8 + c0);
        s.x += p.x; s.y += p.y;
    }
    s.x += b_in[c0]; s.y += b_in[c0 + 1];
    *(float2*)(ws + WS_ZE + (size_t)(b * TN + tt0 + t) * 8 + c0) = s;
}

// ---------------- K1b: LDS-staged argmax over 2 code chunks -> partials ----------------
// grid (128 t-tiles, 4 chunk-pairs) x 256 threads. half = tid>>7 scans chunk 2q+half.
__global__ __launch_bounds__(256) void k1b_search(float* __restrict__ ws) {
    __shared__ float cnL[1024 * 8];   // 32 KB: 2 chunks of normalized codebook
    __shared__ float hL[1024];        // 4 KB
    __shared__ float mbuf[128 * 2 * 2]; // half-1 results: [tp][g] float2, 2 KB
    int tid = threadIdx.x;
    int tile = blockIdx.x, q = blockIdx.y;
    int jbase = q * 1024;
    #pragma unroll
    for (int i = 0; i < 8; i++) {
        int f4 = tid + i * 256;
        *(float4*)(cnL + f4 * 4) = *(const float4*)(ws + WS_CN + (size_t)jbase * 8 + f4 * 4);
    }
    #pragma unroll
    for (int i = 0; i < 4; i++) {
        int o = tid + i * 256;
        hL[o] = ws[WS_C2 + jbase + o];
    }
    __syncthreads();
    int half = tid >> 7, tp = tid & 127;
    int t0 = tile * 256 + tp * 2;
    const float* zp = ws + WS_ZE + (size_t)t0 * 8;
    float4 za0 = *(const float4*)zp,        zb0 = *(const float4*)(zp + 4);
    float4 za1 = *(const float4*)(zp + 8),  zb1 = *(const float4*)(zp + 12);
    float inv0 = 1.0f / fmaxf(sqrtf(dot4(za0, za0) + dot4(zb0, zb0)), 1e-12f);
    float inv1 = 1.0f / fmaxf(sqrtf(dot4(za1, za1) + dot4(zb1, zb1)), 1e-12f);
    float4 ea0 = make_float4(za0.x*inv0, za0.y*inv0, za0.z*inv0, za0.w*inv0);
    float4 eb0 = make_float4(zb0.x*inv0, zb0.y*inv0, zb0.z*inv0, zb0.w*inv0);
    float4 ea1 = make_float4(za1.x*inv1, za1.y*inv1, za1.z*inv1, za1.w*inv1);
    float4 eb1 = make_float4(zb1.x*inv1, zb1.y*inv1, zb1.z*inv1, zb1.w*inv1);
    int j0 = half * 512;   // wave-uniform
    float bs0 = -3.4e38f, bs1 = -3.4e38f;
    int bi0 = 0, bi1 = 0;
    #pragma unroll 4
    for (int j = 0; j < 512; ++j) {
        const float* cr = cnL + (j0 + j) * 8;
        float4 ca = *(const float4*)cr;
        float4 cb = *(const float4*)(cr + 4);
        float hh = hL[j0 + j];
        float s0 = fmaf(ea0.x, ca.x, hh);
        s0 = fmaf(ea0.y, ca.y, s0); s0 = fmaf(ea0.z, ca.z, s0); s0 = fmaf(ea0.w, ca.w, s0);
        s0 = fmaf(eb0.x, cb.x, s0); s0 = fmaf(eb0.y, cb.y, s0);
        s0 = fmaf(eb0.z, cb.z, s0); s0 = fmaf(eb0.w, cb.w, s0);
        float s1 = fmaf(ea1.x, ca.x, hh);
        s1 = fmaf(ea1.y, ca.y, s1); s1 = fmaf(ea1.z, ca.z, s1); s1 = fmaf(ea1.w, ca.w, s1);
        s1 = fmaf(eb1.x, cb.x, s1); s1 = fmaf(eb1.y, cb.y, s1);
        s1 = fmaf(eb1.z, cb.z, s1); s1 = fmaf(eb1.w, cb.w, s1);
        if (s0 > bs0) { bs0 = s0; bi0 = j; }   // strict >: first max == first min dist
        if (s1 > bs1) { bs1 = s1; bi1 = j; }
    }
    int gi0 = jbase + j0 + bi0, gi1 = jbase + j0 + bi1;
    float2* mb = (float2*)mbuf;
    if (half == 1) {
        mb[tp * 2]     = make_float2(bs0, __int_as_float(gi0));
        mb[tp * 2 + 1] = make_float2(bs1, __int_as_float(gi1));
    }
    __syncthreads();
    if (half == 0) {
        float2 o0 = mb[tp * 2], o1 = mb[tp * 2 + 1];
        if (o0.x > bs0) { bs0 = o0.x; gi0 = __float_as_int(o0.y); }  // ties keep lower chunk
        if (o1.x > bs1) { bs1 = o1.x; gi1 = __float_as_int(o1.y); }
        *(float4*)(ws + WS_PART + ((size_t)q * 32768 + t0) * 2) =
            make_float4(bs0, __int_as_float(gi0), bs1, __int_as_float(gi1));
    }
}

// ---------------- K1c: merge 4 partials -> WS_IDX + loss ----------------
__global__ __launch_bounds__(512) void k1c_merge(
    const float* __restrict__ codebook, float* __restrict__ ws) {
    int t = blockIdx.x * 512 + threadIdx.x;
    const float2* part = (const float2*)(ws + WS_PART);
    float2 p = part[t];
    float best = p.x; int bi = __float_as_int(p.y);
    #pragma unroll
    for (int q2 = 1; q2 < 4; q2++) {
        float2 pq = part[q2 * 32768 + t];
        if (pq.x > best) { best = pq.x; bi = __float_as_int(pq.y); }  // ascending: ties keep low
    }
    ((int*)ws)[WS_IDX + t] = bi;
    const float* zep = ws + WS_ZE + (size_t)t * 8;
    float4 za = *(const float4*)zep, zb = *(const float4*)(zep + 4);
    const float* cq = codebook + (size_t)bi * 8;   // raw (un-normalized)
    float4 qa = *(const float4*)cq, qb = *(const float4*)(cq + 4);
    float4 da = make_float4(za.x-qa.x, za.y-qa.y, za.z-qa.z, za.w-qa.w);
    float4 db = make_float4(zb.x-qb.x, zb.y-qb.y, zb.z-qb.z, zb.w-qb.w);
    float l = dot4(da, da) + dot4(db, db);
    for (int off = 32; off >= 1; off >>= 1) l += __shfl_down(l, off, 64);
    if ((threadIdx.x & 63) == 0) atomicAdd(ws + WS_LOSS + (t >> 12), l);
}

// ---------------- K2: out = W_out @ z_q + b_out (fp32) — out region ONLY ----------------
// grid 1024: b = blk>>7, t-tile 128, o-tile 256
__global__ __launch_bounds__(256) void k2_out(
    const float* __restrict__ codebook, const float* __restrict__ b_out,
    float* __restrict__ dout, const float* __restrict__ ws) {
    __shared__ float zq[8 * 128];   // [c][t]
    __shared__ float wl[256 * 8];   // W_out tile [o_local][8]
    __shared__ float bo_l[256];
    int tid = threadIdx.x, blk = blockIdx.x;
    int b = blk >> 7;
    int rem = blk & 127;
    int t0 = (rem >> 2) * 128;
    int o0 = (rem & 3) * 256;
    const int* wsi = (const int*)ws;
    {   // full-block gather: 2 threads per t-row
        int pair = tid >> 1, halfq = tid & 1;
        int idx = wsi[WS_IDX + b * TN + t0 + pair] & (CBN - 1);
        const float* cp = codebook + (size_t)idx * 8 + halfq * 4;
        float4 q4 = *(const float4*)cp;
        int cb = halfq * 4;
        zq[(cb + 0) * 128 + pair] = q4.x;
        zq[(cb + 1) * 128 + pair] = q4.y;
        zq[(cb + 2) * 128 + pair] = q4.z;
        zq[(cb + 3) * 128 + pair] = q4.w;
    }
    bo_l[tid] = b_out[o0 + tid];
    #pragma unroll
    for (int i = 0; i < 2; i++) {
        int f4 = tid + i * 256;
        *(float4*)(wl + f4 * 4) = *(const float4*)(ws + WS_WOUT + o0 * 8 + f4 * 4);
    }
    __syncthreads();
    int t4 = tid & 31, osub = tid >> 5;
    int tq = t4 * 4;
    float4 zr[8];
    #pragma unroll
    for (int c = 0; c < 8; c++) zr[c] = *(float4*)(zq + c * 128 + tq);
    for (int k = 0; k < 32; k++) {
        int ol = osub * 32 + k;
        int o = o0 + ol;
        float4 wa = *(float4*)(wl + ol * 8);
        float4 wb = *(float4*)(wl + ol * 8 + 4);
        float bo = bo_l[ol];
        float4 acc = make_float4(bo, bo, bo, bo);
        float wc[8] = {wa.x, wa.y, wa.z, wa.w, wb.x, wb.y, wb.z, wb.w};
        #pragma unroll
        for (int c = 0; c < 8; c++) {
            acc.x = fmaf(wc[c], zr[c].x, acc.x);
            acc.y = fmaf(wc[c], zr[c].y, acc.y);
            acc.z = fmaf(wc[c], zr[c].z, acc.z);
            acc.w = fmaf(wc[c], zr[c].w, acc.w);
        }
        acc.x = fminf(fmaxf(acc.x, -8.f), 8.f);
        acc.y = fminf(fmaxf(acc.y, -8.f), 8.f);
        acc.z = fminf(fmaxf(acc.z, -8.f), 8.f);
        acc.w = fminf(fmaxf(acc.w, -8.f), 8.f);
        size_t off = ((size_t)(b * DIMN + o)) * TN + (size_t)(t0 + tq);
        *(float4*)(dout + off) = acc;
    }
}

// ---------------- K3: epilogue — fp32 indices + loss ----------------
__global__ __launch_bounds__(256) void k3_epi(
    float* __restrict__ dout, const float* __restrict__ ws) {
    int tid = threadIdx.x, blk = blockIdx.x;
    const int* wsi = (const int*)ws;
    size_t base = (size_t)OUT_ELEMS;
    int i0 = blk * 512 + tid;
    dout[base + (size_t)i0]       = (float)(wsi[WS_IDX + i0] & (CBN - 1));
    dout[base + (size_t)i0 + 256] = (float)(wsi[WS_IDX + i0 + 256] & (CBN - 1));
    if (blk == 0 && tid < 8) {
        float lv = ws[WS_LOSS + tid] * (1.25f / 32768.0f);
        dout[base + (size_t)BTN + (size_t)tid] = lv;
    }
}

extern "C" void kernel_launch(void* const* d_in, const int* in_sizes, int n_in,
                              void* d_out, int out_size, void* d_ws, size_t ws_size,
                              hipStream_t stream) {
    (void)in_sizes; (void)n_in; (void)out_size; (void)ws_size;
    const float* z        = (const float*)d_in[0];
    const float* v_in     = (const float*)d_in[1];
    const float* g_in     = (const float*)d_in[2];
    const float* b_in     = (const float*)d_in[3];
    const float* codebook = (const float*)d_in[4];
    const float* v_out    = (const float*)d_in[5];
    const float* g_out    = (const float*)d_in[6];
    const float* b_out    = (const float*)d_in[7];
    float* out            = (float*)d_out;
    float* ws             = (float*)d_ws;

    hipLaunchKernelGGL(k0_prep, dim3(29), dim3(256), 0, stream,
                       v_in, g_in, codebook, v_out, g_out, ws);
    hipLaunchKernelGGL(k1a_ze, dim3(256), dim3(512), 0, stream, z, b_in, ws);
    hipLaunchKernelGGL(k1b_search, dim3(128, 4), dim3(256), 0, stream, ws);
    hipLaunchKernelGGL(k1c_merge, dim3(64), dim3(512), 0, stream, codebook, ws);
    hipLaunchKernelGGL(k2_out, dim3(1024), dim3(256), 0, stream,
                       codebook, b_out, out, ws);
    hipLaunchKernelGGL(k3_epi, dim3(64), dim3(256), 0, stream, out, ws);
}

// Round 7
// 318.448 us; speedup vs baseline: 1.3682x; 1.0145x over previous
//
#include <hip/hip_runtime.h>

#define DIMN 1024
#define TN 4096
#define BN 8
#define CBN 4096
#define CDN 8
#define BTN (BN*TN)
#define OUT_ELEMS (BN*DIMN*TN)

typedef float fx4 __attribute__((ext_vector_type(4)));

// ws layout (float offsets)
#define WS_WINT 0          // W_in^T scaled: [d][8], 8192 floats
#define WS_WOUT 8192       // W_out scaled: [o][8], 8192 floats
#define WS_CN   16384      // normalized codebook [j][8], 32768 floats
#define WS_C2   49152      // h = -0.5*sum(c_n^2) per code, 4096 floats
#define WS_IDX  53248      // indices (int), 32768
#define WS_LOSS 86016      // 8 floats
#define WS_PART 86024      // (score,idxbits) float2 [4][32768], 262144 floats
#define WS_ZEP  360448     // z_e partials [8][BTN][8], 2097152 floats

__device__ __forceinline__ float dot4(float4 a, float4 b) {
    float d = a.x * b.x;
    d = fmaf(a.y, b.y, d);
    d = fmaf(a.z, b.z, d);
    d = fmaf(a.w, b.w, d);
    return d;
}
__device__ __forceinline__ void add4(float4& a, float4 b) {
    a.x += b.x; a.y += b.y; a.z += b.z; a.w += b.w;
}

// ---------------- K0: prep weights / codebook / zero loss ----------------
__global__ __launch_bounds__(256) void k0_prep(
    const float* __restrict__ v_in, const float* __restrict__ g_in,
    const float* __restrict__ codebook, const float* __restrict__ v_out,
    const float* __restrict__ g_out, float* __restrict__ ws) {
    __shared__ float sred[5];
    int blk = blockIdx.x, tid = threadIdx.x;
    if (blk < 8) {
        int o = blk;
        const float* v = v_in + o * DIMN;
        float4 x = *(const float4*)(v + tid * 4);
        float p = x.x * x.x + x.y * x.y + x.z * x.z + x.w * x.w;
        for (int off = 32; off >= 1; off >>= 1) p += __shfl_down(p, off, 64);
        if ((tid & 63) == 0) sred[tid >> 6] = p;
        __syncthreads();
        if (tid == 0) {
            float tot = sred[0] + sred[1] + sred[2] + sred[3];
            sred[4] = g_in[o] / sqrtf(tot);
        }
        __syncthreads();
        float s = sred[4];
        ws[WS_WINT + (tid * 4 + 0) * 8 + o] = x.x * s;
        ws[WS_WINT + (tid * 4 + 1) * 8 + o] = x.y * s;
        ws[WS_WINT + (tid * 4 + 2) * 8 + o] = x.z * s;
        ws[WS_WINT + (tid * 4 + 3) * 8 + o] = x.w * s;
    } else if (blk < 12) {
        int r = (blk - 8) * 256 + tid;
        const float* v = v_out + r * 8;
        float4 a = *(const float4*)v;
        float4 b = *(const float4*)(v + 4);
        float n2 = dot4(a, a) + dot4(b, b);
        float s = g_out[r] / sqrtf(n2);
        *(float4*)(ws + WS_WOUT + r * 8)     = make_float4(a.x*s, a.y*s, a.z*s, a.w*s);
        *(float4*)(ws + WS_WOUT + r * 8 + 4) = make_float4(b.x*s, b.y*s, b.z*s, b.w*s);
    } else if (blk < 28) {
        int j = (blk - 12) * 256 + tid;
        const float* c = codebook + j * 8;
        float4 a = *(const float4*)c;
        float4 b = *(const float4*)(c + 4);
        float n2 = dot4(a, a) + dot4(b, b);
        float inv = 1.0f / fmaxf(sqrtf(n2), 1e-12f);
        float4 na = make_float4(a.x*inv, a.y*inv, a.z*inv, a.w*inv);
        float4 nb = make_float4(b.x*inv, b.y*inv, b.z*inv, b.w*inv);
        *(float4*)(ws + WS_CN + j * 8)     = na;
        *(float4*)(ws + WS_CN + j * 8 + 4) = nb;
        ws[WS_C2 + j] = -0.5f * (dot4(na, na) + dot4(nb, nb));  // argmin dist == argmax dot+h
    } else {
        if (tid < 8) ws[WS_LOSS + tid] = 0.0f;
    }
}

// ---------------- K1a: z_e partials -> WS_ZEP[p][t][8], p = half*4+wave ----------------
// grid 256: b = blk>>5, tile = (blk&31)>>1 (t-tile 256), half = blk&1 (d 512-chunk).
// Pure stream: float4 z loads (1KB/wave/instr), fma, one partial store. No reduction.
__global__ __launch_bounds__(256) void k1a_ze(
    const float* __restrict__ z, float* __restrict__ ws) {
    __shared__ float wlds[512 * 8];   // 16 KB: W_in^T rows for this half
    int tid = threadIdx.x, blk = blockIdx.x;
    int b = blk >> 5;
    int r = blk & 31;
    int t0 = (r >> 1) * 256;
    int dbase = (r & 1) * 512;
    #pragma unroll
    for (int i = 0; i < 4; i++) {
        int f4 = tid + i * 256;
        *(float4*)(wlds + f4 * 4) = *(const float4*)(ws + WS_WINT + dbase * 8 + f4 * 4);
    }
    __syncthreads();
    int w = tid >> 6, lane = tid & 63;
    const float* zp = z + ((size_t)(b * DIMN + dbase + w * 128)) * TN + t0 + lane * 4;
    float4 acc[8];
    #pragma unroll
    for (int c = 0; c < 8; c++) acc[c] = make_float4(0.f, 0.f, 0.f, 0.f);
    #pragma unroll 8
    for (int dd = 0; dd < 128; ++dd) {
        fx4 zr = __builtin_nontemporal_load((const fx4*)(zp + (size_t)dd * TN));
        const float* wv = wlds + (w * 128 + dd) * 8;   // wave-uniform -> broadcast
        #pragma unroll
        for (int c = 0; c < 8; c++) {
            float wc = wv[c];
            acc[c].x = fmaf(wc, zr.x, acc[c].x);
            acc[c].y = fmaf(wc, zr.y, acc[c].y);
            acc[c].z = fmaf(wc, zr.z, acc[c].z);
            acc[c].w = fmaf(wc, zr.w, acc[c].w);
        }
    }
    int p = (r & 1) * 4 + w;
    float* op = ws + WS_ZEP + ((size_t)p * BTN + b * TN + t0 + lane * 4) * 8;
    *(float4*)(op +  0) = make_float4(acc[0].x, acc[1].x, acc[2].x, acc[3].x);
    *(float4*)(op +  4) = make_float4(acc[4].x, acc[5].x, acc[6].x, acc[7].x);
    *(float4*)(op +  8) = make_float4(acc[0].y, acc[1].y, acc[2].y, acc[3].y);
    *(float4*)(op + 12) = make_float4(acc[4].y, acc[5].y, acc[6].y, acc[7].y);
    *(float4*)(op + 16) = make_float4(acc[0].z, acc[1].z, acc[2].z, acc[3].z);
    *(float4*)(op + 20) = make_float4(acc[4].z, acc[5].z, acc[6].z, acc[7].z);
    *(float4*)(op + 24) = make_float4(acc[0].w, acc[1].w, acc[2].w, acc[3].w);
    *(float4*)(op + 28) = make_float4(acc[4].w, acc[5].w, acc[6].w, acc[7].w);
}

// ---------------- K1b: LDS-staged argmax over 2 code chunks -> partials ----------------
// grid (128 t-tiles, 4 chunk-pairs) x 256 threads. half = tid>>7 scans chunk 2q+half.
__global__ __launch_bounds__(256) void k1b_search(
    const float* __restrict__ b_in, float* __restrict__ ws) {
    __shared__ float cnL[1024 * 8];     // 32 KB
    __shared__ float hL[1024];          // 4 KB
    __shared__ float mbuf[128 * 2 * 2]; // 2 KB
    int tid = threadIdx.x;
    int tile = blockIdx.x, q = blockIdx.y;
    int jbase = q * 1024;
    #pragma unroll
    for (int i = 0; i < 8; i++) {
        int f4 = tid + i * 256;
        *(float4*)(cnL + f4 * 4) = *(const float4*)(ws + WS_CN + (size_t)jbase * 8 + f4 * 4);
    }
    #pragma unroll
    for (int i = 0; i < 4; i++) {
        int o = tid + i * 256;
        hL[o] = ws[WS_C2 + jbase + o];
    }
    int half = tid >> 7, tp = tid & 127;
    int t0 = tile * 256 + tp * 2;
    // assemble z_e = b_in + sum of 8 partials (L2-resident)
    float4 bi0 = *(const float4*)(b_in);
    float4 bi1 = *(const float4*)(b_in + 4);
    float4 za0 = bi0, zb0 = bi1, za1 = bi0, zb1 = bi1;
    #pragma unroll
    for (int p = 0; p < 8; p++) {
        const float* pp = ws + WS_ZEP + ((size_t)p * BTN + t0) * 8;
        add4(za0, *(const float4*)(pp));
        add4(zb0, *(const float4*)(pp + 4));
        add4(za1, *(const float4*)(pp + 8));
        add4(zb1, *(const float4*)(pp + 12));
    }
    __syncthreads();
    float inv0 = 1.0f / fmaxf(sqrtf(dot4(za0, za0) + dot4(zb0, zb0)), 1e-12f);
    float inv1 = 1.0f / fmaxf(sqrtf(dot4(za1, za1) + dot4(zb1, zb1)), 1e-12f);
    float4 ea0 = make_float4(za0.x*inv0, za0.y*inv0, za0.z*inv0, za0.w*inv0);
    float4 eb0 = make_float4(zb0.x*inv0, zb0.y*inv0, zb0.z*inv0, zb0.w*inv0);
    float4 ea1 = make_float4(za1.x*inv1, za1.y*inv1, za1.z*inv1, za1.w*inv1);
    float4 eb1 = make_float4(zb1.x*inv1, zb1.y*inv1, zb1.z*inv1, zb1.w*inv1);
    int j0 = half * 512;   // wave-uniform
    float bs0 = -3.4e38f, bs1 = -3.4e38f;
    int bi = 0, bj = 0;
    #pragma unroll 4
    for (int j = 0; j < 512; ++j) {
        const float* cr = cnL + (j0 + j) * 8;
        float4 ca = *(const float4*)cr;
        float4 cb = *(const float4*)(cr + 4);
        float hh = hL[j0 + j];
        float s0 = fmaf(ea0.x, ca.x, hh);
        s0 = fmaf(ea0.y, ca.y, s0); s0 = fmaf(ea0.z, ca.z, s0); s0 = fmaf(ea0.w, ca.w, s0);
        s0 = fmaf(eb0.x, cb.x, s0); s0 = fmaf(eb0.y, cb.y, s0);
        s0 = fmaf(eb0.z, cb.z, s0); s0 = fmaf(eb0.w, cb.w, s0);
        float s1 = fmaf(ea1.x, ca.x, hh);
        s1 = fmaf(ea1.y, ca.y, s1); s1 = fmaf(ea1.z, ca.z, s1); s1 = fmaf(ea1.w, ca.w, s1);
        s1 = fmaf(eb1.x, cb.x, s1); s1 = fmaf(eb1.y, cb.y, s1);
        s1 = fmaf(eb1.z, cb.z, s1); s1 = fmaf(eb1.w, cb.w, s1);
        if (s0 > bs0) { bs0 = s0; bi = j; }   // strict >: first max == first-min dist
        if (s1 > bs1) { bs1 = s1; bj = j; }
    }
    int gi0 = jbase + j0 + bi, gi1 = jbase + j0 + bj;
    float2* mb = (float2*)mbuf;
    if (half == 1) {
        mb[tp * 2]     = make_float2(bs0, __int_as_float(gi0));
        mb[tp * 2 + 1] = make_float2(bs1, __int_as_float(gi1));
    }
    __syncthreads();
    if (half == 0) {
        float2 o0 = mb[tp * 2], o1 = mb[tp * 2 + 1];
        if (o0.x > bs0) { bs0 = o0.x; gi0 = __float_as_int(o0.y); }  // ties keep lower chunk
        if (o1.x > bs1) { bs1 = o1.x; gi1 = __float_as_int(o1.y); }
        *(float4*)(ws + WS_PART + ((size_t)q * 32768 + t0) * 2) =
            make_float4(bs0, __int_as_float(gi0), bs1, __int_as_float(gi1));
    }
}

// ---------------- K1c: merge 4 partials -> WS_IDX + float idx out + loss atomics ----------------
__global__ __launch_bounds__(512) void k1c_merge(
    const float* __restrict__ codebook, const float* __restrict__ b_in,
    float* __restrict__ dout, float* __restrict__ ws) {
    int t = blockIdx.x * 512 + threadIdx.x;
    const float2* part = (const float2*)(ws + WS_PART);
    float2 p = part[t];
    float best = p.x; int bi = __float_as_int(p.y);
    #pragma unroll
    for (int q2 = 1; q2 < 4; q2++) {
        float2 pq = part[q2 * 32768 + t];
        if (pq.x > best) { best = pq.x; bi = __float_as_int(pq.y); }  // ascending: ties keep low
    }
    ((int*)ws)[WS_IDX + t] = bi;
    dout[(size_t)OUT_ELEMS + t] = (float)bi;
    // z_e = b_in + sum partials
    float4 za = *(const float4*)(b_in);
    float4 zb = *(const float4*)(b_in + 4);
    #pragma unroll
    for (int pi = 0; pi < 8; pi++) {
        const float* pp = ws + WS_ZEP + ((size_t)pi * BTN + t) * 8;
        add4(za, *(const float4*)(pp));
        add4(zb, *(const float4*)(pp + 4));
    }
    const float* cq = codebook + (size_t)bi * 8;   // raw (un-normalized)
    float4 qa = *(const float4*)cq, qb = *(const float4*)(cq + 4);
    float4 da = make_float4(za.x-qa.x, za.y-qa.y, za.z-qa.z, za.w-qa.w);
    float4 db = make_float4(zb.x-qb.x, zb.y-qb.y, zb.z-qb.z, zb.w-qb.w);
    float l = dot4(da, da) + dot4(db, db);
    for (int off = 32; off >= 1; off >>= 1) l += __shfl_down(l, off, 64);
    if ((threadIdx.x & 63) == 0) atomicAdd(ws + WS_LOSS + (t >> 12), l);
}

// ---------------- K2: out = W_out @ z_q + b_out (fp32, nt store) + loss finalize ----------------
// grid 1025: blocks 0..1023: b = blk>>7, t-tile 128, o-tile 256. block 1024: loss.
__global__ __launch_bounds__(256) void k2_out(
    const float* __restrict__ codebook, const float* __restrict__ b_out,
    float* __restrict__ dout, const float* __restrict__ ws) {
    __shared__ float zq[8 * 128];
    __shared__ float wl[256 * 8];
    __shared__ float bo_l[256];
    int tid = threadIdx.x, blk = blockIdx.x;
    if (blk == 1024) {
        if (tid < 8) {
            float lv = ws[WS_LOSS + tid] * (1.25f / 32768.0f);
            dout[(size_t)OUT_ELEMS + BTN + tid] = lv;
        }
        return;
    }
    int b = blk >> 7;
    int rem = blk & 127;
    int t0 = (rem >> 2) * 128;
    int o0 = (rem & 3) * 256;
    const int* wsi = (const int*)ws;
    {   // full-block gather: 2 threads per t-row
        int pair = tid >> 1, halfq = tid & 1;
        int idx = wsi[WS_IDX + b * TN + t0 + pair] & (CBN - 1);
        const float* cp = codebook + (size_t)idx * 8 + halfq * 4;
        float4 q4 = *(const float4*)cp;
        int cb = halfq * 4;
        zq[(cb + 0) * 128 + pair] = q4.x;
        zq[(cb + 1) * 128 + pair] = q4.y;
        zq[(cb + 2) * 128 + pair] = q4.z;
        zq[(cb + 3) * 128 + pair] = q4.w;
    }
    bo_l[tid] = b_out[o0 + tid];
    #pragma unroll
    for (int i = 0; i < 2; i++) {
        int f4 = tid + i * 256;
        *(float4*)(wl + f4 * 4) = *(const float4*)(ws + WS_WOUT + o0 * 8 + f4 * 4);
    }
    __syncthreads();
    int t4 = tid & 31, osub = tid >> 5;
    int tq = t4 * 4;
    float4 zr[8];
    #pragma unroll
    for (int c = 0; c < 8; c++) zr[c] = *(float4*)(zq + c * 128 + tq);
    for (int k = 0; k < 32; k++) {
        int ol = osub * 32 + k;
        int o = o0 + ol;
        float4 wa = *(float4*)(wl + ol * 8);
        float4 wb = *(float4*)(wl + ol * 8 + 4);
        float bo = bo_l[ol];
        float4 acc = make_float4(bo, bo, bo, bo);
        float wc[8] = {wa.x, wa.y, wa.z, wa.w, wb.x, wb.y, wb.z, wb.w};
        #pragma unroll
        for (int c = 0; c < 8; c++) {
            acc.x = fmaf(wc[c], zr[c].x, acc.x);
            acc.y = fmaf(wc[c], zr[c].y, acc.y);
            acc.z = fmaf(wc[c], zr[c].z, acc.z);
            acc.w = fmaf(wc[c], zr[c].w, acc.w);
        }
        acc.x = fminf(fmaxf(acc.x, -8.f), 8.f);
        acc.y = fminf(fmaxf(acc.y, -8.f), 8.f);
        acc.z = fminf(fmaxf(acc.z, -8.f), 8.f);
        acc.w = fminf(fmaxf(acc.w, -8.f), 8.f);
        size_t off = ((size_t)(b * DIMN + o)) * TN + (size_t)(t0 + tq);
        fx4 st; st.x = acc.x; st.y = acc.y; st.z = acc.z; st.w = acc.w;
        __builtin_nontemporal_store(st, (fx4*)(dout + off));
    }
}

extern "C" void kernel_launch(void* const* d_in, const int* in_sizes, int n_in,
                              void* d_out, int out_size, void* d_ws, size_t ws_size,
                              hipStream_t stream) {
    (void)in_sizes; (void)n_in; (void)out_size; (void)ws_size;
    const float* z        = (const float*)d_in[0];
    const float* v_in     = (const float*)d_in[1];
    const float* g_in     = (const float*)d_in[2];
    const float* b_in     = (const float*)d_in[3];
    const float* codebook = (const float*)d_in[4];
    const float* v_out    = (const float*)d_in[5];
    const float* g_out    = (const float*)d_in[6];
    const float* b_out    = (const float*)d_in[7];
    float* out            = (float*)d_out;
    float* ws             = (float*)d_ws;

    hipLaunchKernelGGL(k0_prep, dim3(29), dim3(256), 0, stream,
                       v_in, g_in, codebook, v_out, g_out, ws);
    hipLaunchKernelGGL(k1a_ze, dim3(256), dim3(256), 0, stream, z, ws);
    hipLaunchKernelGGL(k1b_search, dim3(128, 4), dim3(256), 0, stream, b_in, ws);
    hipLaunchKernelGGL(k1c_merge, dim3(64), dim3(512), 0, stream,
                       codebook, b_in, out, ws);
    hipLaunchKernelGGL(k2_out, dim3(1025), dim3(256), 0, stream,
                       codebook, b_out, out, ws);
}